// Round 2
// baseline (79.173 us; speedup 1.0000x reference)
//
#include <hip/hip_runtime.h>
#include <hip/hip_bf16.h>

// Problem constants
#define BB 8
#define NN 1024
#define FF 2048
#define CC 4
#define HH 1024
#define ROWS (BB * NN)        // 8192
#define MELEMS (8 * FF)       // 16384 folded weights (rows 0-3: p1 (W1a), 4-7: p2 (W1b))

typedef float f4 __attribute__((ext_vector_type(4)));

__device__ __forceinline__ float sigmoidf_fast(float x) {
    return __builtin_amdgcn_rcpf(1.0f + __expf(-x));
}

// Multi-value butterfly: reduce 8 per-lane values across 64 lanes with 10 shuffles.
// Returns (in every lane) the full sum of original value index
// vidx = ((lane&1)<<2) | (lane&2) | ((lane>>2)&1)   (bit-reversed lane&7).
__device__ __forceinline__ float butterfly8(float a[8], int lane) {
    #pragma unroll
    for (int i = 0; i < 4; ++i) {
        float send = (lane & 1) ? a[i] : a[i + 4];
        float got = __shfl_xor(send, 1, 64);
        a[i] = ((lane & 1) ? a[i + 4] : a[i]) + got;
    }
    #pragma unroll
    for (int i = 0; i < 2; ++i) {
        float send = (lane & 2) ? a[i] : a[i + 2];
        float got = __shfl_xor(send, 2, 64);
        a[i] = ((lane & 2) ? a[i + 2] : a[i]) + got;
    }
    {
        float send = (lane & 4) ? a[0] : a[1];
        float got = __shfl_xor(send, 4, 64);
        a[0] = ((lane & 4) ? a[1] : a[0]) + got;
    }
    a[0] += __shfl_xor(a[0], 8, 64);
    a[0] += __shfl_xor(a[0], 16, 64);
    a[0] += __shfl_xor(a[0], 32, 64);
    return a[0];
}

// K1: partial folded weights, float4 over k.
// Mpart[chunk][half*4+c][f] = sum_{h in chunk} W2[c,h] * W1[h, half*F + f]
__global__ __launch_bounds__(256) void k_fold(const float* __restrict__ W1,
                                              const float* __restrict__ W2,
                                              float* __restrict__ Mpart,
                                              int hper) {
    int k4 = (blockIdx.x * 256 + threadIdx.x) << 2;   // 0..4092 step 4 (grid.x = 4)
    int chunk = blockIdx.y;
    int half = k4 >> 11;
    int f = k4 & (FF - 1);
    int h0 = chunk * hper;
    f4 a0 = {0.f, 0.f, 0.f, 0.f}, a1 = a0, a2 = a0, a3 = a0;
    const float* base = W1 + (size_t)h0 * (2 * FF) + k4;
    #pragma unroll 4
    for (int i = 0; i < hper; ++i) {
        f4 wv = __builtin_nontemporal_load((const f4*)(base + (size_t)i * (2 * FF)));
        int h = h0 + i;   // uniform per block -> scalar loads of W2
        float s0 = W2[0 * HH + h], s1 = W2[1 * HH + h];
        float s2 = W2[2 * HH + h], s3 = W2[3 * HH + h];
        a0 += wv * s0;
        a1 += wv * s1;
        a2 += wv * s2;
        a3 += wv * s3;
    }
    float* mp = Mpart + (size_t)chunk * MELEMS + (size_t)(half * 4) * FF + f;
    *(f4*)(mp + 0 * FF) = a0;
    *(f4*)(mp + 1 * FF) = a1;
    *(f4*)(mp + 2 * FF) = a2;
    *(f4*)(mp + 3 * FF) = a3;
}

// K1b: reduce partials into M; block 64 computes cst[c] = W2[c,:]@b1 + b2[c]
__global__ __launch_bounds__(256) void k_reduce(const float* __restrict__ Mpart,
                                                const float* __restrict__ W2,
                                                const float* __restrict__ b1,
                                                const float* __restrict__ b2,
                                                float* __restrict__ M,
                                                float* __restrict__ cst,
                                                int nchunks) {
    if (blockIdx.x < 64) {
        int idx = blockIdx.x * 256 + threadIdx.x;   // 0..16383
        float s = 0.f;
        #pragma unroll 8
        for (int p = 0; p < nchunks; ++p) s += Mpart[(size_t)p * MELEMS + idx];
        M[idx] = s;
    } else {
        int t = threadIdx.x;
        int c = t >> 6, lane = t & 63;
        float s = 0.f;
        for (int h = lane; h < HH; h += 64) s += W2[c * HH + h] * b1[h];
        #pragma unroll
        for (int off = 32; off; off >>= 1) s += __shfl_down(s, off);
        if (lane == 0) cst[c] = s + b2[c];
    }
}

// K2: P1/P2 row-dots with register-resident folded weights + fused vectors passthrough.
// Thread t owns f-slice [8t, 8t+8). 8 rows/block, batches of 4 rows between syncs.
__global__ __launch_bounds__(256) void k_pcompute(const float* __restrict__ v,
                                                  const float* __restrict__ M,
                                                  const float* __restrict__ cst,
                                                  float* __restrict__ outv,
                                                  float* __restrict__ P1,
                                                  float* __restrict__ P2f) {
    int t = threadIdx.x;
    int lane = t & 63, wvi = t >> 6;
    int f0 = t * 8;
    float w[8][8];
    #pragma unroll
    for (int j = 0; j < 8; ++j) {
        f4 a = *(const f4*)(M + j * FF + f0);
        f4 b = *(const f4*)(M + j * FF + f0 + 4);
        w[j][0] = a[0]; w[j][1] = a[1]; w[j][2] = a[2]; w[j][3] = a[3];
        w[j][4] = b[0]; w[j][5] = b[1]; w[j][6] = b[2]; w[j][7] = b[3];
    }
    int vidx = ((lane & 1) << 2) | (lane & 2) | ((lane >> 2) & 1);
    __shared__ float red[4][32];
    int row0 = blockIdx.x * 8;

    #pragma unroll
    for (int batch = 0; batch < 2; ++batch) {
        float fin[4];
        #pragma unroll
        for (int r = 0; r < 4; ++r) {
            int row = row0 + batch * 4 + r;
            const f4* vr = (const f4*)(v + (size_t)row * FF + f0);
            f4 a = __builtin_nontemporal_load(vr);
            f4 b = __builtin_nontemporal_load(vr + 1);
            f4* po = (f4*)(outv + (size_t)row * FF + f0);
            __builtin_nontemporal_store(a, po);
            __builtin_nontemporal_store(b, po + 1);
            float x[8] = {a[0], a[1], a[2], a[3], b[0], b[1], b[2], b[3]};
            float acc[8];
            #pragma unroll
            for (int j = 0; j < 8; ++j) {
                float s = 0.f;
                #pragma unroll
                for (int k = 0; k < 8; ++k) s += x[k] * w[j][k];
                acc[j] = s;
            }
            fin[r] = butterfly8(acc, lane);
        }
        if (lane < 8) {
            #pragma unroll
            for (int r = 0; r < 4; ++r) red[r][wvi * 8 + vidx] = fin[r];
        }
        __syncthreads();
        if (t < 32) {
            int r = t >> 3, j = t & 7;
            float s = red[r][j] + red[r][8 + j] + red[r][16 + j] + red[r][24 + j];
            int row = row0 + batch * 4 + r;
            if (j < 4) P1[j * ROWS + row] = s;
            else       P2f[(j - 4) * ROWS + row] = s + cst[j - 4];  // fold const here
        }
        __syncthreads();
    }
}

// K3: conn[b][c][j][i] = sigmoid(P1[c][b*N+i] + P2f[c][b*N+j])
__global__ __launch_bounds__(256) void k_conn(const float* __restrict__ P1,
                                              const float* __restrict__ P2f,
                                              float* __restrict__ out) {
    int t = threadIdx.x;
    const int nrows = BB * CC * NN;   // 32768
    for (int r = blockIdx.x; r < nrows; r += gridDim.x) {
        int b = r >> 12;
        int c = (r >> 10) & 3;
        int j = r & (NN - 1);
        float s = P2f[c * ROWS + b * NN + j];
        const f4* p1 = (const f4*)(P1 + c * ROWS + b * NN);
        f4 p = p1[t];                 // 256 threads x f4 = 1024 = N
        f4 rs;
        rs[0] = sigmoidf_fast(p[0] + s);
        rs[1] = sigmoidf_fast(p[1] + s);
        rs[2] = sigmoidf_fast(p[2] + s);
        rs[3] = sigmoidf_fast(p[3] + s);
        __builtin_nontemporal_store(rs, (f4*)(out + (size_t)r * NN) + t);
    }
}

extern "C" void kernel_launch(void* const* d_in, const int* in_sizes, int n_in,
                              void* d_out, int out_size, void* d_ws, size_t ws_size,
                              hipStream_t stream) {
    const float* vectors = (const float*)d_in[0];
    const float* W1 = (const float*)d_in[1];
    const float* b1 = (const float*)d_in[2];
    const float* W2 = (const float*)d_in[3];
    const float* b2 = (const float*)d_in[4];

    float* out_vectors = (float*)d_out;                       // B*N*F floats
    float* out_conn = (float*)d_out + (size_t)ROWS * FF;      // B*C*N*N floats

    // pick fold parallelism by available workspace
    int nchunks = 16;
    {
        size_t fixed = (size_t)MELEMS + 16 + 2 * (size_t)CC * ROWS;
        if (ws_size >= ((size_t)64 * MELEMS + fixed) * sizeof(float)) nchunks = 64;
        else if (ws_size >= ((size_t)32 * MELEMS + fixed) * sizeof(float)) nchunks = 32;
    }
    int hper = HH / nchunks;

    float* w = (float*)d_ws;
    float* Mpart = w;
    float* M     = Mpart + (size_t)nchunks * MELEMS;
    float* cst   = M + MELEMS;
    float* P1    = cst + 16;
    float* P2f   = P1 + (size_t)CC * ROWS;

    k_fold<<<dim3(4, nchunks), 256, 0, stream>>>(W1, W2, Mpart, hper);
    k_reduce<<<65, 256, 0, stream>>>(Mpart, W2, b1, b2, M, cst, nchunks);
    k_pcompute<<<ROWS / 8, 256, 0, stream>>>(vectors, M, cst, out_vectors, P1, P2f);
    k_conn<<<8192, 256, 0, stream>>>(P1, P2f, out_conn);
}

// Round 3
// 70.796 us; speedup vs baseline: 1.1183x; 1.1183x over previous
//
#include <hip/hip_runtime.h>
#include <hip/hip_bf16.h>

// Problem constants
#define BB 8
#define NN 1024
#define FF 2048
#define CC 4
#define HH 1024
#define ROWS (BB * NN)        // 8192
#define MELEMS (8 * FF)       // 16384 folded weights (rows 0-3: p1 (W1a), 4-7: p2 (W1b))

typedef float f4 __attribute__((ext_vector_type(4)));

__device__ __forceinline__ float sigmoidf_fast(float x) {
    return __builtin_amdgcn_rcpf(1.0f + __expf(-x));
}

// Multi-value butterfly: reduce 8 per-lane values across 64 lanes with 10 shuffles.
// Full sum of value index vidx = ((lane&1)<<2) | (lane&2) | ((lane>>2)&1) ends in a[0].
__device__ __forceinline__ float butterfly8(float a[8], int lane) {
    #pragma unroll
    for (int i = 0; i < 4; ++i) {
        float send = (lane & 1) ? a[i] : a[i + 4];
        float got = __shfl_xor(send, 1, 64);
        a[i] = ((lane & 1) ? a[i + 4] : a[i]) + got;
    }
    #pragma unroll
    for (int i = 0; i < 2; ++i) {
        float send = (lane & 2) ? a[i] : a[i + 2];
        float got = __shfl_xor(send, 2, 64);
        a[i] = ((lane & 2) ? a[i + 2] : a[i]) + got;
    }
    {
        float send = (lane & 4) ? a[0] : a[1];
        float got = __shfl_xor(send, 4, 64);
        a[0] = ((lane & 4) ? a[1] : a[0]) + got;
    }
    a[0] += __shfl_xor(a[0], 8, 64);
    a[0] += __shfl_xor(a[0], 16, 64);
    a[0] += __shfl_xor(a[0], 32, 64);
    return a[0];
}

// K1: partial folded weights, float4 over k.
// Mpart[chunk][half*4+c][f] = sum_{h in chunk} W2[c,h] * W1[h, half*F + f]
__global__ __launch_bounds__(256) void k_fold(const float* __restrict__ W1,
                                              const float* __restrict__ W2,
                                              float* __restrict__ Mpart,
                                              int hper) {
    int k4 = (blockIdx.x * 256 + threadIdx.x) << 2;   // 0..4092 step 4 (grid.x = 4)
    int chunk = blockIdx.y;
    int half = k4 >> 11;
    int f = k4 & (FF - 1);
    int h0 = chunk * hper;
    f4 a0 = {0.f, 0.f, 0.f, 0.f}, a1 = a0, a2 = a0, a3 = a0;
    const float* base = W1 + (size_t)h0 * (2 * FF) + k4;
    #pragma unroll 4
    for (int i = 0; i < hper; ++i) {
        f4 wv = *(const f4*)(base + (size_t)i * (2 * FF));
        int h = h0 + i;   // uniform per block -> scalar loads of W2
        float s0 = W2[0 * HH + h], s1 = W2[1 * HH + h];
        float s2 = W2[2 * HH + h], s3 = W2[3 * HH + h];
        a0 += wv * s0;
        a1 += wv * s1;
        a2 += wv * s2;
        a3 += wv * s3;
    }
    float* mp = Mpart + (size_t)chunk * MELEMS + (size_t)(half * 4) * FF + f;
    *(f4*)(mp + 0 * FF) = a0;
    *(f4*)(mp + 1 * FF) = a1;
    *(f4*)(mp + 2 * FF) = a2;
    *(f4*)(mp + 3 * FF) = a3;
}

// K1b: reduce partials into M; block 64 computes cst[c] = W2[c,:]@b1 + b2[c]
__global__ __launch_bounds__(256) void k_reduce(const float* __restrict__ Mpart,
                                                const float* __restrict__ W2,
                                                const float* __restrict__ b1,
                                                const float* __restrict__ b2,
                                                float* __restrict__ M,
                                                float* __restrict__ cst,
                                                int nchunks) {
    if (blockIdx.x < 64) {
        int idx = blockIdx.x * 256 + threadIdx.x;   // 0..16383
        float s = 0.f;
        #pragma unroll 8
        for (int p = 0; p < nchunks; ++p) s += Mpart[(size_t)p * MELEMS + idx];
        M[idx] = s;
    } else {
        int t = threadIdx.x;
        int c = t >> 6, lane = t & 63;
        float s = 0.f;
        for (int h = lane; h < HH; h += 64) s += W2[c * HH + h] * b1[h];
        #pragma unroll
        for (int off = 32; off; off >>= 1) s += __shfl_down(s, off);
        if (lane == 0) cst[c] = s + b2[c];
    }
}

// K2: P1/P2 row-dots with register-resident folded weights + fused vectors passthrough.
// Thread t owns f-slice [8t, 8t+8). 8 rows/block, batches of 4 rows.
// Phase-split per batch: (1) issue all 8 loads, (2) all 8 stores, (3) compute —
// keeps 128 B/lane in flight so the HBM-cold vectors stream pipelines.
__global__ __launch_bounds__(256) void k_pcompute(const float* __restrict__ v,
                                                  const float* __restrict__ M,
                                                  const float* __restrict__ cst,
                                                  float* __restrict__ outv,
                                                  float* __restrict__ P1,
                                                  float* __restrict__ P2f) {
    int t = threadIdx.x;
    int lane = t & 63, wvi = t >> 6;
    int f0 = t * 8;
    float w[8][8];
    #pragma unroll
    for (int j = 0; j < 8; ++j) {
        f4 a = *(const f4*)(M + j * FF + f0);
        f4 b = *(const f4*)(M + j * FF + f0 + 4);
        w[j][0] = a[0]; w[j][1] = a[1]; w[j][2] = a[2]; w[j][3] = a[3];
        w[j][4] = b[0]; w[j][5] = b[1]; w[j][6] = b[2]; w[j][7] = b[3];
    }
    int vidx = ((lane & 1) << 2) | (lane & 2) | ((lane >> 2) & 1);
    __shared__ float red[4][32];
    int row0 = blockIdx.x * 8;

    #pragma unroll
    for (int batch = 0; batch < 2; ++batch) {
        int rb = row0 + batch * 4;
        f4 va[4], vb[4];
        // phase 1: issue all loads back-to-back
        #pragma unroll
        for (int r = 0; r < 4; ++r) {
            const f4* vr = (const f4*)(v + (size_t)(rb + r) * FF + f0);
            va[r] = vr[0];
            vb[r] = vr[1];
        }
        // phase 2: passthrough stores
        #pragma unroll
        for (int r = 0; r < 4; ++r) {
            f4* po = (f4*)(outv + (size_t)(rb + r) * FF + f0);
            po[0] = va[r];
            po[1] = vb[r];
        }
        // phase 3: compute + reduce
        float fin[4];
        #pragma unroll
        for (int r = 0; r < 4; ++r) {
            float x[8] = {va[r][0], va[r][1], va[r][2], va[r][3],
                          vb[r][0], vb[r][1], vb[r][2], vb[r][3]};
            float acc[8];
            #pragma unroll
            for (int j = 0; j < 8; ++j) {
                float s = 0.f;
                #pragma unroll
                for (int k = 0; k < 8; ++k) s += x[k] * w[j][k];
                acc[j] = s;
            }
            fin[r] = butterfly8(acc, lane);
        }
        if (lane < 8) {
            #pragma unroll
            for (int r = 0; r < 4; ++r) red[r][wvi * 8 + vidx] = fin[r];
        }
        __syncthreads();
        if (t < 32) {
            int r = t >> 3, j = t & 7;
            float s = red[r][j] + red[r][8 + j] + red[r][16 + j] + red[r][24 + j];
            int row = rb + r;
            if (j < 4) P1[j * ROWS + row] = s;
            else       P2f[(j - 4) * ROWS + row] = s + cst[j - 4];  // fold const here
        }
        __syncthreads();
    }
}

// K3: conn[b][c][j][i] = sigmoid(P1[c][b*N+i] + P2f[c][b*N+j])
// 8192 blocks, compile-time 4 unrolled row-iterations for load/store pipelining.
__global__ __launch_bounds__(256) void k_conn(const float* __restrict__ P1,
                                              const float* __restrict__ P2f,
                                              float* __restrict__ out) {
    int t = threadIdx.x;
    #pragma unroll
    for (int it = 0; it < 4; ++it) {
        int r = blockIdx.x + it * 8192;   // 0..32767
        int b = r >> 12;
        int c = (r >> 10) & 3;
        int j = r & (NN - 1);
        float s = P2f[c * ROWS + b * NN + j];
        const f4* p1 = (const f4*)(P1 + c * ROWS + b * NN);
        f4 p = p1[t];                 // 256 threads x f4 = 1024 = N
        f4 rs;
        rs[0] = sigmoidf_fast(p[0] + s);
        rs[1] = sigmoidf_fast(p[1] + s);
        rs[2] = sigmoidf_fast(p[2] + s);
        rs[3] = sigmoidf_fast(p[3] + s);
        *((f4*)(out + (size_t)r * NN) + t) = rs;
    }
}

extern "C" void kernel_launch(void* const* d_in, const int* in_sizes, int n_in,
                              void* d_out, int out_size, void* d_ws, size_t ws_size,
                              hipStream_t stream) {
    const float* vectors = (const float*)d_in[0];
    const float* W1 = (const float*)d_in[1];
    const float* b1 = (const float*)d_in[2];
    const float* W2 = (const float*)d_in[3];
    const float* b2 = (const float*)d_in[4];

    float* out_vectors = (float*)d_out;                       // B*N*F floats
    float* out_conn = (float*)d_out + (size_t)ROWS * FF;      // B*C*N*N floats

    // pick fold parallelism by available workspace
    int nchunks = 16;
    {
        size_t fixed = (size_t)MELEMS + 16 + 2 * (size_t)CC * ROWS;
        if (ws_size >= ((size_t)64 * MELEMS + fixed) * sizeof(float)) nchunks = 64;
        else if (ws_size >= ((size_t)32 * MELEMS + fixed) * sizeof(float)) nchunks = 32;
    }
    int hper = HH / nchunks;

    float* w = (float*)d_ws;
    float* Mpart = w;
    float* M     = Mpart + (size_t)nchunks * MELEMS;
    float* cst   = M + MELEMS;
    float* P1    = cst + 16;
    float* P2f   = P1 + (size_t)CC * ROWS;

    k_fold<<<dim3(4, nchunks), 256, 0, stream>>>(W1, W2, Mpart, hper);
    k_reduce<<<65, 256, 0, stream>>>(Mpart, W2, b1, b2, M, cst, nchunks);
    k_pcompute<<<ROWS / 8, 256, 0, stream>>>(vectors, M, cst, out_vectors, P1, P2f);
    k_conn<<<8192, 256, 0, stream>>>(P1, P2f, out_conn);
}